// Round 16
// baseline (176.164 us; speedup 1.0000x reference)
//
#include <hip/hip_runtime.h>
#include <hip/hip_bf16.h>

// ---------------- problem constants ----------------
#define NTOK   8192
#define TOPK   2
#define NROWS  (NTOK*TOPK)      // 16384
#define NEXP   8
#define KDIM   1024             // inner (INTER)
#define NDIM   2048             // output (HIDDEN)
#define TM     128              // tile rows
#define TN     128              // tile cols
#define BK     32
#define MAXYT  136              // sum ceil(cnt_e/128) <= 128+8
#define NXT    (NDIM/TN)        // 16
#define GRID_G (MAXYT*NXT)      // 2176 = 8*272

typedef __bf16 bf16_t;
typedef __bf16 bf16x8 __attribute__((ext_vector_type(8)));
typedef float  f32x4  __attribute__((ext_vector_type(4)));

static_assert(sizeof(bf16x8) == 16, "bf16x8 must be 16B");

// ---------------- ws layout (bytes) ----------------
#define OFF_TW    ((size_t)0)                    // 16384 f32
#define OFF_INV   ((size_t)(1<<16))              // 16384 i32
#define OFF_CNT   ((size_t)(1<<17))              // 8 i32
#define OFF_RL    ((size_t)(1<<18))              // 8*16384 i32
#define OFF_XP    ((size_t)(1<<20))              // 16384*1024 bf16 = 32MB (permuted)
#define OFF_WB    ((size_t)(34u<<20))            // 8*2048*1024 bf16 = 32MB
#define OFF_SCR   ((size_t)(68u<<20))            // 16384*2048 bf16 = 64MB (permuted order)

__device__ __forceinline__ void gload_lds16(const bf16_t* g, const char* l) {
  __builtin_amdgcn_global_load_lds(
      (const __attribute__((address_space(1))) void*)g,
      (__attribute__((address_space(3))) void*)(void*)l, 16, 0, 0);
}

#define CVT8(lo,hi) bf16x8{ (bf16_t)(lo).x,(bf16_t)(lo).y,(bf16_t)(lo).z,(bf16_t)(lo).w, \
                            (bf16_t)(hi).x,(bf16_t)(hi).y,(bf16_t)(hi).z,(bf16_t)(hi).w }

// ---------------- 1. routing: softmax + top2, LDS-aggregated bucket ----------
__global__ void routing_kernel(const float* __restrict__ logits,
                               float* __restrict__ tw,
                               int* __restrict__ cnt, int* __restrict__ rowlist) {
  __shared__ int lcnt[NEXP];
  __shared__ int lbase[NEXP];
  int tid = threadIdx.x;
  int t = blockIdx.x * blockDim.x + tid;
  if (tid < NEXP) lcnt[tid] = 0;
  __syncthreads();

  float4 a = *(const float4*)(logits + (size_t)t*NEXP);
  float4 b = *(const float4*)(logits + (size_t)t*NEXP + 4);
  float l[8] = {a.x, a.y, a.z, a.w, b.x, b.y, b.z, b.w};
  float m = l[0];
#pragma unroll
  for (int i = 1; i < 8; i++) m = fmaxf(m, l[i]);
  float p[8], s = 0.f;
#pragma unroll
  for (int i = 0; i < 8; i++) { p[i] = __expf(l[i] - m); s += p[i]; }
  int e0 = 0; float b0 = p[0];
#pragma unroll
  for (int i = 1; i < 8; i++) if (p[i] > b0) { b0 = p[i]; e0 = i; }
  int e1 = (e0 == 0) ? 1 : 0; float b1 = p[e1];
#pragma unroll
  for (int i = 0; i < 8; i++) if (i != e0 && p[i] > b1) { b1 = p[i]; e1 = i; }
  float inv = 1.f / s;
  tw[2*t]   = b0 * inv;
  tw[2*t+1] = b1 * inv;

  int lp0 = atomicAdd(&lcnt[e0], 1);
  int lp1 = atomicAdd(&lcnt[e1], 1);
  __syncthreads();
  if (tid < NEXP) lbase[tid] = atomicAdd(&cnt[tid], lcnt[tid]);
  __syncthreads();
  rowlist[(size_t)e0*NROWS + lbase[e0] + lp0] = 2*t;
  rowlist[(size_t)e1*NROWS + lbase[e1] + lp1] = 2*t + 1;
}

// ---------------- 2. fused cvt: cvt_x_perm (blocks 0..2047) + cvt_w (2048..6143)
__global__ void cvt_kernel(const float* __restrict__ x,
                           const int* __restrict__ cnt,
                           const int* __restrict__ rowlist,
                           bf16_t* __restrict__ xp,
                           int* __restrict__ inv,
                           const float* __restrict__ w,
                           bf16_t* __restrict__ wb) {
  __shared__ float tf[64*65];
  int bid = blockIdx.x;
  int tid = threadIdx.x;

  if (bid < 2048) {
    int rid = bid * 8 + (tid >> 6);              // slot 0..16383
    int c   = (tid & 63) * 16;                   // col start
    int e = 0, base = 0, acc = 0;
#pragma unroll
    for (int ee = 0; ee < NEXP; ee++) {
      int ce = cnt[ee];
      if (rid >= acc && rid < acc + ce) { e = ee; base = acc; }
      acc += ce;
    }
    int src = rowlist[(size_t)e*NROWS + (rid - base)];
    const float* sp = x + (size_t)src*KDIM + c;
    float4 v0 = *(const float4*)(sp);
    float4 v1 = *(const float4*)(sp + 4);
    float4 v2 = *(const float4*)(sp + 8);
    float4 v3 = *(const float4*)(sp + 12);
    bf16_t* dp = xp + (size_t)rid*KDIM + c;
    *(bf16x8*)(dp)     = CVT8(v0, v1);
    *(bf16x8*)(dp + 8) = CVT8(v2, v3);
    if ((tid & 63) == 0) inv[src] = rid;
    return;
  }

  int id = bid - 2048;               // 0..4095
  int e  = id >> 9;                  // 0..7
  int k0 = ((id >> 5) & 15) * 64;    // 0..960
  int n0 = (id & 31) * 64;           // 0..1984
  const float* src = w + (size_t)e*KDIM*NDIM + (size_t)k0*NDIM + n0;
#pragma unroll
  for (int i = 0; i < 2; i++) {
    int idx = tid + i*512;           // 0..1023
    int kr  = idx >> 4;
    int nc4 = (idx & 15) * 4;
    float4 v = *(const float4*)(src + (size_t)kr*NDIM + nc4);
    tf[kr*65 + nc4+0] = v.x; tf[kr*65 + nc4+1] = v.y;
    tf[kr*65 + nc4+2] = v.z; tf[kr*65 + nc4+3] = v.w;
  }
  __syncthreads();
  bf16_t* dst = wb + (size_t)e*NDIM*KDIM + (size_t)n0*KDIM + k0;
  {
    int idx = tid;                   // 0..511
    int nr  = idx >> 3;
    int kc  = (idx & 7) * 8;
    bf16x8 o;
#pragma unroll
    for (int j = 0; j < 8; j++) o[j] = (bf16_t)tf[(kc+j)*65 + nr];
    *(bf16x8*)(dst + (size_t)nr*KDIM + kc) = o;
  }
}

// ---------------- 3. GEMM: 128x128, BK=32, 4-buffer deep pipeline ------------
// 4 waves (2M x 2N). Per tile kt: STAGE(t kt+2 -> buf[(kt+2)&3], 4 DMAs);
// vmcnt(8) (drains tile kt only; kt+1, kt+2 stay in flight); raw s_barrier;
// asm ds_read_b128 frags (invisible to waitcnt pass -> no forced drain);
// lgkmcnt(0)+sched_barrier; 16 MFMA in setprio(1).
// Stage target was read 2 barriers ago -> race-free with 1 barrier/tile.
// Buffer: A[128][32] 8KB + B[128][32] 8KB = 16KB; x4 = 64KB -> 2 blocks/CU.
// Swizzle (r11, 0 conflicts measured): phys 16B slot = logical ^ ((row>>1)&3).
#define DSREAD(dst, addr, IMM) \
  asm volatile("ds_read_b128 %0, %1 offset:" #IMM : "=v"(dst) : "v"(addr))

#define STAGE(BI) do {                                                         \
    const char* dA = smem + (unsigned)(BI)*16384u + t*16;                      \
    const char* dB = dA + 8192;                                                \
    gload_lds16(gA0, dA); gload_lds16(gA1, dA + 4096);                         \
    gload_lds16(gB0, dB); gload_lds16(gB1, dB + 4096);                         \
    gA0 += BK; gA1 += BK; gB0 += BK; gB1 += BK;                                \
  } while (0)

#define VMCNT(n) asm volatile("s_waitcnt vmcnt(" #n ")" ::: "memory")

#define COMPUTE(BI) do {                                                       \
    unsigned ab = sbase + (unsigned)(BI)*16384u + aoff0;                       \
    unsigned bb = sbase + (unsigned)(BI)*16384u + 8192u + boff0;               \
    bf16x8 A0,A1,A2,A3,B0,B1,B2,B3;                                            \
    DSREAD(A0, ab, 0);    DSREAD(A1, ab, 1024);                                \
    DSREAD(A2, ab, 2048); DSREAD(A3, ab, 3072);                                \
    DSREAD(B0, bb, 0);    DSREAD(B1, bb, 1024);                                \
    DSREAD(B2, bb, 2048); DSREAD(B3, bb, 3072);                                \
    asm volatile("s_waitcnt lgkmcnt(0)" ::: "memory");                         \
    __builtin_amdgcn_sched_barrier(0);                                         \
    __builtin_amdgcn_s_setprio(1);                                             \
    bf16x8 A_[4] = {A0,A1,A2,A3};                                              \
    bf16x8 B_[4] = {B0,B1,B2,B3};                                              \
    _Pragma("unroll") for (int mi = 0; mi < 4; mi++)                           \
      _Pragma("unroll") for (int ni = 0; ni < 4; ni++)                         \
        acc[mi][ni] = __builtin_amdgcn_mfma_f32_16x16x32_bf16(                 \
            A_[mi], B_[ni], acc[mi][ni], 0, 0, 0);                             \
    __builtin_amdgcn_s_setprio(0);                                             \
  } while (0)

__global__ __launch_bounds__(256)
void gemm_kernel(const bf16_t* __restrict__ xp,     // [NROWS][KDIM] permuted
                 const bf16_t* __restrict__ wb,     // [NEXP][NDIM][KDIM]
                 const int*    __restrict__ cnt,
                 bf16_t*       __restrict__ scrb) { // [NROWS][NDIM] permuted
  __shared__ char smem[65536];

  // XCD-bijective swizzle: 2176 = 8*272, n-tile fastest
  int bid = blockIdx.x;
  int lin = (bid & 7) * (GRID_G/8) + (bid >> 3);
  int xt  = lin & (NXT-1);
  int yt  = lin >> 4;

  // inline worklist: expert + row range for this 128-row tile
  int e = -1, rowbase = 0, nrows = 0;
  {
    int a0 = 0, rb = 0;
#pragma unroll
    for (int ee = 0; ee < NEXP; ee++) {
      int c  = cnt[ee];
      int nt = (c + TM - 1) >> 7;
      if (yt >= a0 && yt < a0 + nt) {
        e = ee; rowbase = rb + (yt - a0)*TM;
        nrows = c - (yt - a0)*TM; if (nrows > TM) nrows = TM;
      }
      a0 += nt; rb += c;
    }
  }
  if (e < 0) return;
  const int n0 = xt * TN;

  const int t    = threadIdx.x;
  const int lane = t & 63;
  const int wv   = t >> 6;         // 0..3
  const int wm   = wv >> 1;        // 0..1
  const int wn   = wv & 1;         // 0..1
  const int lr   = lane & 15;
  const int l4   = lane >> 4;

  const unsigned sbase = (unsigned)(uintptr_t)
      (__attribute__((address_space(3))) char*)(void*)smem;

  // ---- staging: thread t -> rows t>>2 and 64+(t>>2), phys slot t&3 ----
  const int koff = ((t & 3) ^ ((t >> 3) & 3)) * 8;
  int a0r = rowbase + (t >> 2);       if (a0r > NROWS-1) a0r = NROWS-1;
  int a1r = rowbase + (t >> 2) + 64;  if (a1r > NROWS-1) a1r = NROWS-1;
  const bf16_t* gA0 = xp + (size_t)a0r*KDIM + koff;
  const bf16_t* gA1 = xp + (size_t)a1r*KDIM + koff;
  const bf16_t* gB0 = wb + ((size_t)e*NDIM + n0 + (t >> 2))*KDIM + koff;
  const bf16_t* gB1 = gB0 + (size_t)64*KDIM;

  // ---- fragment read offsets (byte, swizzled; rows 64B) ----
  const unsigned aoff0 = (wm*64 + lr)*64 + ((l4 ^ ((lr >> 1) & 3)) << 4);
  const unsigned boff0 = (wn*64 + lr)*64 + ((l4 ^ ((lr >> 1) & 3)) << 4);

  f32x4 acc[4][4] = {};

  // ---- prologue: stage tiles 0,1 ----
  STAGE(0);
  STAGE(1);

  // ---- main loop: tiles 0..29 (stage kt+2, distance-2) ----
#pragma unroll 1
  for (int kt = 0; kt < 30; ++kt) {
    STAGE((kt + 2) & 3);
    VMCNT(8);                        // tile kt's 4 DMAs landed; 8 still flying
    __builtin_amdgcn_s_barrier();
    COMPUTE(kt & 3);
  }
  // ---- tail: tiles 30, 31 ----
  VMCNT(4);
  __builtin_amdgcn_s_barrier();
  COMPUTE(2);
  VMCNT(0);
  __builtin_amdgcn_s_barrier();
  COMPUTE(3);

  // ---- epilogue: sequential slot rows ----
#pragma unroll
  for (int mi = 0; mi < 4; mi++) {
#pragma unroll
    for (int jj = 0; jj < 4; jj++) {
      int rbw = wm*64 + mi*16 + l4*4 + jj;
      if (rbw < nrows) {
        bf16_t* dst = scrb + (size_t)(rowbase + rbw)*NDIM + n0 + wn*64 + lr;
#pragma unroll
        for (int ni = 0; ni < 4; ni++) dst[ni*16] = (bf16_t)acc[mi][ni][jj];
      }
    }
  }
}

// ---------------- 4. reduce: 16 cols/thread, 4 indep 16B loads ---------------
__global__ void reduce_kernel(const bf16_t* __restrict__ scr,
                              const int* __restrict__ inv,
                              const float* __restrict__ tw,
                              float* __restrict__ out) {
  int g  = blockIdx.x * 512 + threadIdx.x;
  int tk = g >> 7;                     // 128 threads per token
  int c  = (g & 127) * 16;
  int2  iv = *(const int2*)(inv + 2*tk);
  float w0 = tw[2*tk], w1 = tw[2*tk+1];
  const bf16_t* pa = scr + (size_t)iv.x*NDIM + c;
  const bf16_t* pb = scr + (size_t)iv.y*NDIM + c;
  bf16x8 a0 = *(const bf16x8*)(pa);
  bf16x8 a1 = *(const bf16x8*)(pa + 8);
  bf16x8 b0 = *(const bf16x8*)(pb);
  bf16x8 b1 = *(const bf16x8*)(pb + 8);
  float* dst = out + (size_t)tk*NDIM + c;
#pragma unroll
  for (int h = 0; h < 2; h++) {
    bf16x8 av = h ? a1 : a0;
    bf16x8 bv = h ? b1 : b0;
    float4 o0 = { w0*(float)av[0]+w1*(float)bv[0], w0*(float)av[1]+w1*(float)bv[1],
                  w0*(float)av[2]+w1*(float)bv[2], w0*(float)av[3]+w1*(float)bv[3] };
    float4 o1 = { w0*(float)av[4]+w1*(float)bv[4], w0*(float)av[5]+w1*(float)bv[5],
                  w0*(float)av[6]+w1*(float)bv[6], w0*(float)av[7]+w1*(float)bv[7] };
    *(float4*)(dst + h*8)     = o0;
    *(float4*)(dst + h*8 + 4) = o1;
  }
}

// ---------------- launch ----------------
extern "C" void kernel_launch(void* const* d_in, const int* in_sizes, int n_in,
                              void* d_out, int out_size, void* d_ws, size_t ws_size,
                              hipStream_t stream) {
  const float* x      = (const float*)d_in[0];
  const float* w      = (const float*)d_in[1];
  const float* logits = (const float*)d_in[2];
  float* out = (float*)d_out;

  char* ws = (char*)d_ws;
  float*  tw      = (float*)(ws + OFF_TW);
  int*    inv     = (int*)  (ws + OFF_INV);
  int*    cnt     = (int*)  (ws + OFF_CNT);
  int*    rowlist = (int*)  (ws + OFF_RL);
  bf16_t* xp      = (bf16_t*)(ws + OFF_XP);
  bf16_t* wb      = (bf16_t*)(ws + OFF_WB);
  bf16_t* scrb    = (bf16_t*)(ws + OFF_SCR);

  hipMemsetAsync(cnt, 0, NEXP * sizeof(int), stream);
  routing_kernel<<<NTOK/256, 256, 0, stream>>>(logits, tw, cnt, rowlist);
  cvt_kernel<<<2048 + 4096, 512, 0, stream>>>(x, cnt, rowlist, xp, inv, w, wb);
  gemm_kernel<<<GRID_G, 256, 0, stream>>>(xp, wb, cnt, scrb);
  reduce_kernel<<<NTOK*NDIM/16/512, 512, 0, stream>>>(scrb, inv, tw, out);
}

// Round 17
// 157.899 us; speedup vs baseline: 1.1157x; 1.1157x over previous
//
#include <hip/hip_runtime.h>
#include <hip/hip_bf16.h>

// ---------------- problem constants ----------------
#define NTOK   8192
#define TOPK   2
#define NROWS  (NTOK*TOPK)      // 16384
#define NEXP   8
#define KDIM   1024             // inner (INTER)
#define NDIM   2048             // output (HIDDEN)
#define TM     128              // tile rows
#define TN     256              // tile cols
#define BK     64
#define MAXYT  136              // sum ceil(cnt_e/128) <= 128+8
#define NXT    (NDIM/TN)        // 8
#define GRID_G (MAXYT*NXT)      // 1088 = 8*136

typedef __bf16 bf16_t;
typedef __bf16 bf16x8 __attribute__((ext_vector_type(8)));
typedef float  f32x4  __attribute__((ext_vector_type(4)));

static_assert(sizeof(bf16x8) == 16, "bf16x8 must be 16B");

// ---------------- ws layout (bytes) ----------------
#define OFF_TW    ((size_t)0)                    // 16384 f32
#define OFF_INV   ((size_t)(1<<16))              // 16384 i32
#define OFF_CNT   ((size_t)(1<<17))              // 8 i32
#define OFF_RL    ((size_t)(1<<18))              // 8*16384 i32
#define OFF_XP    ((size_t)(1<<20))              // 16384*1024 bf16 = 32MB (permuted)
#define OFF_WB    ((size_t)(34u<<20))            // 8*2048*1024 bf16 = 32MB
#define OFF_SCR   ((size_t)(68u<<20))            // 16384*2048 bf16 = 64MB (permuted order)

__device__ __forceinline__ void gload_lds16(const bf16_t* g, const char* l) {
  __builtin_amdgcn_global_load_lds(
      (const __attribute__((address_space(1))) void*)g,
      (__attribute__((address_space(3))) void*)(void*)l, 16, 0, 0);
}

#define CVT8(lo,hi) bf16x8{ (bf16_t)(lo).x,(bf16_t)(lo).y,(bf16_t)(lo).z,(bf16_t)(lo).w, \
                            (bf16_t)(hi).x,(bf16_t)(hi).y,(bf16_t)(hi).z,(bf16_t)(hi).w }

// ---------------- 1. routing: softmax + top2, LDS-aggregated bucket ----------
__global__ void routing_kernel(const float* __restrict__ logits,
                               float* __restrict__ tw,
                               int* __restrict__ cnt, int* __restrict__ rowlist) {
  __shared__ int lcnt[NEXP];
  __shared__ int lbase[NEXP];
  int tid = threadIdx.x;
  int t = blockIdx.x * blockDim.x + tid;
  if (tid < NEXP) lcnt[tid] = 0;
  __syncthreads();

  float4 a = *(const float4*)(logits + (size_t)t*NEXP);
  float4 b = *(const float4*)(logits + (size_t)t*NEXP + 4);
  float l[8] = {a.x, a.y, a.z, a.w, b.x, b.y, b.z, b.w};
  float m = l[0];
#pragma unroll
  for (int i = 1; i < 8; i++) m = fmaxf(m, l[i]);
  float p[8], s = 0.f;
#pragma unroll
  for (int i = 0; i < 8; i++) { p[i] = __expf(l[i] - m); s += p[i]; }
  int e0 = 0; float b0 = p[0];
#pragma unroll
  for (int i = 1; i < 8; i++) if (p[i] > b0) { b0 = p[i]; e0 = i; }
  int e1 = (e0 == 0) ? 1 : 0; float b1 = p[e1];
#pragma unroll
  for (int i = 0; i < 8; i++) if (i != e0 && p[i] > b1) { b1 = p[i]; e1 = i; }
  float inv = 1.f / s;
  tw[2*t]   = b0 * inv;
  tw[2*t+1] = b1 * inv;

  int lp0 = atomicAdd(&lcnt[e0], 1);
  int lp1 = atomicAdd(&lcnt[e1], 1);
  __syncthreads();
  if (tid < NEXP) lbase[tid] = atomicAdd(&cnt[tid], lcnt[tid]);
  __syncthreads();
  rowlist[(size_t)e0*NROWS + lbase[e0] + lp0] = 2*t;
  rowlist[(size_t)e1*NROWS + lbase[e1] + lp1] = 2*t + 1;
}

// ---------------- 2. fused cvt: cvt_x_perm (blocks 0..2047) + cvt_w (2048..6143)
__global__ void cvt_kernel(const float* __restrict__ x,
                           const int* __restrict__ cnt,
                           const int* __restrict__ rowlist,
                           bf16_t* __restrict__ xp,
                           int* __restrict__ inv,
                           const float* __restrict__ w,
                           bf16_t* __restrict__ wb) {
  __shared__ float tf[64*65];
  int bid = blockIdx.x;
  int tid = threadIdx.x;

  if (bid < 2048) {
    // ---------- cvt_x_perm: 8 rows/block, 64 thr/row, 16 cols/thread ----------
    int rid = bid * 8 + (tid >> 6);              // slot 0..16383
    int c   = (tid & 63) * 16;                   // col start
    int e = 0, base = 0, acc = 0;
#pragma unroll
    for (int ee = 0; ee < NEXP; ee++) {
      int ce = cnt[ee];
      if (rid >= acc && rid < acc + ce) { e = ee; base = acc; }
      acc += ce;
    }
    int src = rowlist[(size_t)e*NROWS + (rid - base)];
    const float* sp = x + (size_t)src*KDIM + c;
    float4 v0 = *(const float4*)(sp);
    float4 v1 = *(const float4*)(sp + 4);
    float4 v2 = *(const float4*)(sp + 8);
    float4 v3 = *(const float4*)(sp + 12);
    bf16_t* dp = xp + (size_t)rid*KDIM + c;
    *(bf16x8*)(dp)     = CVT8(v0, v1);
    *(bf16x8*)(dp + 8) = CVT8(v2, v3);
    if ((tid & 63) == 0) inv[src] = rid;
    return;
  }

  // ---------- cvt_w: 64n x 64k tile ----------
  int id = bid - 2048;               // 0..4095
  int e  = id >> 9;                  // 0..7
  int k0 = ((id >> 5) & 15) * 64;    // 0..960
  int n0 = (id & 31) * 64;           // 0..1984
  const float* src = w + (size_t)e*KDIM*NDIM + (size_t)k0*NDIM + n0;
#pragma unroll
  for (int i = 0; i < 2; i++) {
    int idx = tid + i*512;           // 0..1023
    int kr  = idx >> 4;
    int nc4 = (idx & 15) * 4;
    float4 v = *(const float4*)(src + (size_t)kr*NDIM + nc4);
    tf[kr*65 + nc4+0] = v.x; tf[kr*65 + nc4+1] = v.y;
    tf[kr*65 + nc4+2] = v.z; tf[kr*65 + nc4+3] = v.w;
  }
  __syncthreads();
  bf16_t* dst = wb + (size_t)e*NDIM*KDIM + (size_t)n0*KDIM + k0;
  {
    int idx = tid;                   // 0..511
    int nr  = idx >> 3;
    int kc  = (idx & 7) * 8;
    bf16x8 o;
#pragma unroll
    for (int j = 0; j < 8; j++) o[j] = (bf16_t)tf[(kc+j)*65 + nr];
    *(bf16x8*)(dst + (size_t)nr*KDIM + kc) = o;
  }
}

// ---------------- 3. dense per-expert GEMM: 128x256, BK=64 (r8/r12-proven) ---
__global__ __launch_bounds__(512)
void gemm_kernel(const bf16_t* __restrict__ xp,     // [NROWS][KDIM] permuted
                 const bf16_t* __restrict__ wb,     // [NEXP][NDIM][KDIM]
                 const int*    __restrict__ cnt,
                 bf16_t*       __restrict__ scrb) { // [NROWS][NDIM] permuted
  __shared__ char smem[49152];

  // XCD-bijective swizzle: 1088 = 8*136, n-tile fastest
  int bid = blockIdx.x;
  int lin = (bid & 7) * (GRID_G/8) + (bid >> 3);
  int xt  = lin & (NXT-1);
  int yt  = lin >> 3;

  // inline worklist: expert + row range for this 128-row tile
  int e = -1, rowbase = 0, nrows = 0;
  {
    int a0 = 0, rb = 0;
#pragma unroll
    for (int ee = 0; ee < NEXP; ee++) {
      int c  = cnt[ee];
      int nt = (c + TM - 1) >> 7;
      if (yt >= a0 && yt < a0 + nt) {
        e = ee; rowbase = rb + (yt - a0)*TM;
        nrows = c - (yt - a0)*TM; if (nrows > TM) nrows = TM;
      }
      a0 += nt; rb += c;
    }
  }
  if (e < 0) return;
  const int n0 = xt * TN;

  const int t    = threadIdx.x;
  const int lane = t & 63;
  const int wv   = t >> 6;         // 0..7
  const int wm   = wv >> 2;        // 0..1
  const int wn   = wv & 3;         // 0..3
  const int lr   = lane & 15;
  const int l4   = lane >> 4;

  // ---- staging: thread t -> row t>>3 (+64i), phys slot t&7, dest linear ----
  const int koff = ((t & 7) ^ ((t >> 3) & 7)) * 8;
  int ar0 = rowbase + (t >> 3);       if (ar0 > NROWS-1) ar0 = NROWS-1;
  int ar1 = rowbase + (t >> 3) + 64;  if (ar1 > NROWS-1) ar1 = NROWS-1;
  const bf16_t* gA0 = xp + (size_t)ar0*KDIM + koff;
  const bf16_t* gA1 = xp + (size_t)ar1*KDIM + koff;
  const bf16_t* gBb = wb + ((size_t)e*NDIM + n0 + (t >> 3))*KDIM + koff;
  const char* dA = &smem[t*16];
  const char* dB = &smem[16384 + t*16];

  // ---- fragment read offsets (byte, swizzled) ----
  const int aoff0 = (wm*64 + lr)*128 + ((l4 ^ (lr & 7)) << 4);
  const int boff0 = 16384 + (wn*64 + lr)*128 + ((l4 ^ (lr & 7)) << 4);

  f32x4 acc[4][4] = {};

#pragma unroll 1
  for (int kt = 0; kt < KDIM/BK; ++kt) {
    __syncthreads();                 // previous reads done
    gload_lds16(gA0, dA);
    gload_lds16(gA1, dA + 8192);
    gload_lds16(gBb,            dB);
    gload_lds16(gBb + 64*KDIM,  dB + 8192);
    gload_lds16(gBb + 128*KDIM, dB + 16384);
    gload_lds16(gBb + 192*KDIM, dB + 24576);
    gA0 += BK; gA1 += BK; gBb += BK;
    __syncthreads();                 // staged data visible

    bf16x8 af[4][2], bf[4][2];
#pragma unroll
    for (int mi = 0; mi < 4; mi++) {
      af[mi][0] = *(const bf16x8*)&smem[aoff0 + mi*2048];
      af[mi][1] = *(const bf16x8*)&smem[(aoff0 + mi*2048) ^ 64];
    }
#pragma unroll
    for (int ni = 0; ni < 4; ni++) {
      bf[ni][0] = *(const bf16x8*)&smem[boff0 + ni*2048];
      bf[ni][1] = *(const bf16x8*)&smem[(boff0 + ni*2048) ^ 64];
    }
#pragma unroll
    for (int mi = 0; mi < 4; mi++)
#pragma unroll
      for (int ni = 0; ni < 4; ni++) {
        acc[mi][ni] = __builtin_amdgcn_mfma_f32_16x16x32_bf16(af[mi][0], bf[ni][0], acc[mi][ni], 0, 0, 0);
        acc[mi][ni] = __builtin_amdgcn_mfma_f32_16x16x32_bf16(af[mi][1], bf[ni][1], acc[mi][ni], 0, 0, 0);
      }
  }

  // ---- epilogue: sequential slot rows ----
#pragma unroll
  for (int mi = 0; mi < 4; mi++) {
#pragma unroll
    for (int jj = 0; jj < 4; jj++) {
      int rbw = wm*64 + mi*16 + l4*4 + jj;
      if (rbw < nrows) {
        bf16_t* dst = scrb + (size_t)(rowbase + rbw)*NDIM + n0 + wn*64 + lr;
#pragma unroll
        for (int ni = 0; ni < 4; ni++) dst[ni*16] = (bf16_t)acc[mi][ni][jj];
      }
    }
  }
}

// ---------------- 4. reduce: 16 cols/thread -> 4 indep 16B loads in flight ---
__global__ void reduce_kernel(const bf16_t* __restrict__ scr,
                              const int* __restrict__ inv,
                              const float* __restrict__ tw,
                              float* __restrict__ out) {
  int g  = blockIdx.x * 512 + threadIdx.x;
  int tk = g >> 7;                     // 128 threads per token
  int c  = (g & 127) * 16;
  int2  iv = *(const int2*)(inv + 2*tk);
  float w0 = tw[2*tk], w1 = tw[2*tk+1];
  const bf16_t* pa = scr + (size_t)iv.x*NDIM + c;
  const bf16_t* pb = scr + (size_t)iv.y*NDIM + c;
  bf16x8 a0 = *(const bf16x8*)(pa);
  bf16x8 a1 = *(const bf16x8*)(pa + 8);
  bf16x8 b0 = *(const bf16x8*)(pb);
  bf16x8 b1 = *(const bf16x8*)(pb + 8);
  float* dst = out + (size_t)tk*NDIM + c;
#pragma unroll
  for (int h = 0; h < 2; h++) {
    bf16x8 av = h ? a1 : a0;
    bf16x8 bv = h ? b1 : b0;
    float4 o0 = { w0*(float)av[0]+w1*(float)bv[0], w0*(float)av[1]+w1*(float)bv[1],
                  w0*(float)av[2]+w1*(float)bv[2], w0*(float)av[3]+w1*(float)bv[3] };
    float4 o1 = { w0*(float)av[4]+w1*(float)bv[4], w0*(float)av[5]+w1*(float)bv[5],
                  w0*(float)av[6]+w1*(float)bv[6], w0*(float)av[7]+w1*(float)bv[7] };
    *(float4*)(dst + h*8)     = o0;
    *(float4*)(dst + h*8 + 4) = o1;
  }
}

// ---------------- launch ----------------
extern "C" void kernel_launch(void* const* d_in, const int* in_sizes, int n_in,
                              void* d_out, int out_size, void* d_ws, size_t ws_size,
                              hipStream_t stream) {
  const float* x      = (const float*)d_in[0];
  const float* w      = (const float*)d_in[1];
  const float* logits = (const float*)d_in[2];
  float* out = (float*)d_out;

  char* ws = (char*)d_ws;
  float*  tw      = (float*)(ws + OFF_TW);
  int*    inv     = (int*)  (ws + OFF_INV);
  int*    cnt     = (int*)  (ws + OFF_CNT);
  int*    rowlist = (int*)  (ws + OFF_RL);
  bf16_t* xp      = (bf16_t*)(ws + OFF_XP);
  bf16_t* wb      = (bf16_t*)(ws + OFF_WB);
  bf16_t* scrb    = (bf16_t*)(ws + OFF_SCR);

  hipMemsetAsync(cnt, 0, NEXP * sizeof(int), stream);
  routing_kernel<<<NTOK/256, 256, 0, stream>>>(logits, tw, cnt, rowlist);
  cvt_kernel<<<2048 + 4096, 512, 0, stream>>>(x, cnt, rowlist, xp, inv, w, wb);
  gemm_kernel<<<GRID_G, 512, 0, stream>>>(xp, wb, cnt, scrb);
  reduce_kernel<<<NTOK*NDIM/16/512, 512, 0, stream>>>(scrb, inv, tw, out);
}